// Round 1
// baseline (1187.634 us; speedup 1.0000x reference)
//
#include <hip/hip_runtime.h>
#include <cstdint>
#include <cstddef>

#define H 8
#define D 1024
#define HD 128
#define Bv 32
#define Mv 196
#define BM 6272      // Bv*Mv
#define MP 208       // padded token rows per (b,h)
#define NP 224       // padded cols for P / v2T (7*32)

typedef __bf16 bf16_t;
typedef __bf16 bf16x8 __attribute__((ext_vector_type(8)));
typedef __bf16 bf16x4 __attribute__((ext_vector_type(4)));
typedef float  f32x4  __attribute__((ext_vector_type(4)));

__device__ __forceinline__ void gl_lds16(const void* g, void* l) {
  __builtin_amdgcn_global_load_lds((const __attribute__((address_space(1))) void*)g,
                                   (__attribute__((address_space(3))) void*)l, 16, 0, 0);
}

__device__ __forceinline__ f32x4 mfma_bf16(bf16x8 a, bf16x8 b, f32x4 c) {
  return __builtin_amdgcn_mfma_f32_16x16x32_bf16(a, b, c, 0, 0, 0);
}

// ---------------- f32 -> bf16 convert ----------------
__global__ __launch_bounds__(256) void cvt_kernel(const float* __restrict__ s,
                                                  bf16_t* __restrict__ d, int n) {
  int i = (blockIdx.x * 256 + threadIdx.x) * 4;
  const int stride = gridDim.x * 256 * 4;
  for (; i < n; i += stride) {
    float4 v = *(const float4*)(s + i);
    bf16x4 o;
    o[0] = (bf16_t)v.x; o[1] = (bf16_t)v.y; o[2] = (bf16_t)v.z; o[3] = (bf16_t)v.w;
    *(bf16x4*)(d + i) = o;
  }
}

// ---------------- fused projection: GEMM + bias + CELU + per-head groupnorm ----------------
// grid (49, 8, 4): x = 128-row tile, y = head, z = projection {q2,k,v1,v2}
__global__ __launch_bounds__(256) void proj_kernel(
    const bf16_t* __restrict__ Xb, const bf16_t* __restrict__ Wall,
    const float* __restrict__ b0, const float* __restrict__ b1,
    const float* __restrict__ b2, const float* __restrict__ b3,
    const float* __restrict__ w0, const float* __restrict__ w1,
    const float* __restrict__ w2, const float* __restrict__ w3,
    const float* __restrict__ c0, const float* __restrict__ c1,
    const float* __restrict__ c2, const float* __restrict__ c3,
    int layer,
    bf16_t* __restrict__ oq2, bf16_t* __restrict__ ok,
    bf16_t* __restrict__ ov1, bf16_t* __restrict__ ov2T)
{
  __shared__ __align__(16) char smem[16384 + 2048];
  bf16_t* lA = (bf16_t*)smem;            // [128][32]
  bf16_t* lB = (bf16_t*)(smem + 8192);   // [128][32]
  float*  red = (float*)(smem + 16384);  // [2][128][2]

  const int tid = threadIdx.x;
  const int w = tid >> 6, lane = tid & 63;
  const int g = lane >> 4, li = lane & 15;
  const int wr = w >> 1, wc = w & 1;
  const int rt = blockIdx.x, h = blockIdx.y, p = blockIdx.z;
  const int row0 = rt * 128;

  const bf16_t* Wp = Wall + ((size_t)p * 3 + layer) * (1024u * 1024u) + (size_t)h * 128 * 1024;

  // staging geometry: per thread 2 lds-loads for A, 2 for B; 16B each, linear LDS
  const int idx0 = w * 1024 + lane * 16;
  const int r0 = idx0 >> 6, cc0 = (idx0 >> 4) & 3;
  const int idx1 = idx0 + 4096;
  const int r1 = idx1 >> 6, cc1 = (idx1 >> 4) & 3;

  const bf16_t* gA0 = Xb + (size_t)(row0 + r0) * 1024 + cc0 * 8;
  const bf16_t* gA1 = Xb + (size_t)(row0 + r1) * 1024 + cc1 * 8;
  const bf16_t* gB0 = Wp + (size_t)r0 * 1024 + cc0 * 8;
  const bf16_t* gB1 = Wp + (size_t)r1 * 1024 + cc1 * 8;
  char* lA0 = smem + w * 1024;
  char* lA1 = smem + w * 1024 + 4096;
  char* lB0 = smem + 8192 + w * 1024;
  char* lB1 = smem + 8192 + w * 1024 + 4096;

  f32x4 acc[4][4] = {};

  for (int kt = 0; kt < 32; ++kt) {
    const int k0 = kt * 32;
    gl_lds16(gA0 + k0, lA0);
    gl_lds16(gA1 + k0, lA1);
    gl_lds16(gB0 + k0, lB0);
    gl_lds16(gB1 + k0, lB1);
    __syncthreads();
    bf16x8 af[4], bfr[4];
#pragma unroll
    for (int mi = 0; mi < 4; ++mi)
      af[mi] = *(const bf16x8*)(lA + (wr * 64 + mi * 16 + li) * 32 + g * 8);
#pragma unroll
    for (int ni = 0; ni < 4; ++ni)
      bfr[ni] = *(const bf16x8*)(lB + (wc * 64 + ni * 16 + li) * 32 + g * 8);
#pragma unroll
    for (int mi = 0; mi < 4; ++mi)
#pragma unroll
      for (int ni = 0; ni < 4; ++ni)
        acc[mi][ni] = mfma_bf16(af[mi], bfr[ni], acc[mi][ni]);
    __syncthreads();
  }

  const float* bias = (p == 0 ? b0 : p == 1 ? b1 : p == 2 ? b2 : b3) + layer * 1024 + h * 128;
  const float* gwp  = (p == 0 ? w0 : p == 1 ? w1 : p == 2 ? w2 : w3) + layer * 1024 + h * 128;
  const float* gbp  = (p == 0 ? c0 : p == 1 ? c1 : p == 2 ? c2 : c3) + layer * 1024 + h * 128;

  float bia[4], gwv[4], gbv[4];
#pragma unroll
  for (int ni = 0; ni < 4; ++ni) {
    const int ct = wc * 64 + ni * 16 + li;
    bia[ni] = bias[ct]; gwv[ni] = gwp[ct]; gbv[ni] = gbp[ct];
  }

  // bias + CELU in place
#pragma unroll
  for (int mi = 0; mi < 4; ++mi)
#pragma unroll
    for (int ni = 0; ni < 4; ++ni)
#pragma unroll
      for (int q = 0; q < 4; ++q) {
        float v = acc[mi][ni][q] + bia[ni];
        acc[mi][ni][q] = v > 0.f ? v : 1.3f * expm1f(v * (1.0f / 1.3f));
      }

  // per-row (per-head, 128 elems) stats: in-wave 16-lane reduce + cross-wave via LDS
#pragma unroll
  for (int mi = 0; mi < 4; ++mi)
#pragma unroll
    for (int q = 0; q < 4; ++q) {
      float s = 0.f, ss = 0.f;
#pragma unroll
      for (int ni = 0; ni < 4; ++ni) { float v = acc[mi][ni][q]; s += v; ss += v * v; }
#pragma unroll
      for (int msk = 1; msk < 16; msk <<= 1) {
        s  += __shfl_xor(s,  msk, 64);
        ss += __shfl_xor(ss, msk, 64);
      }
      if (li == 0) {
        const int row = wr * 64 + mi * 16 + g * 4 + q;
        red[(wc * 128 + row) * 2 + 0] = s;
        red[(wc * 128 + row) * 2 + 1] = ss;
      }
    }
  __syncthreads();

#pragma unroll
  for (int mi = 0; mi < 4; ++mi)
#pragma unroll
    for (int q = 0; q < 4; ++q) {
      const int row = wr * 64 + mi * 16 + g * 4 + q;
      const float s  = red[row * 2]     + red[(128 + row) * 2];
      const float ss = red[row * 2 + 1] + red[(128 + row) * 2 + 1];
      const float mean = s * (1.f / 128.f);
      const float var  = ss * (1.f / 128.f) - mean * mean;
      const float rs = rsqrtf(var + 1e-5f);
      const int rg = row0 + row;
      const int bb = rg / 196;
      const int mm = rg - bb * 196;
      const size_t bh = (size_t)(bb * 8 + h);
#pragma unroll
      for (int ni = 0; ni < 4; ++ni) {
        const int ct = wc * 64 + ni * 16 + li;
        const float o = (acc[mi][ni][q] - mean) * rs * gwv[ni] + gbv[ni];
        const bf16_t ob = (bf16_t)o;
        if (p == 0)      oq2[(bh * MP + mm) * HD + ct] = ob;
        else if (p == 1) ok [(bh * MP + mm) * HD + ct] = ob;
        else if (p == 2) ov1[(bh * MP + mm) * HD + ct] = ob;
        else             ov2T[(bh * HD + ct) * NP + mm] = ob;   // transposed for PV B-operand
      }
    }
}

// ---------------- attention + gate ----------------
// grid 512: blockIdx.x = (b*8+h)*2 + half; 256 threads = 4 waves; wave handles 16-row m-tiles
__global__ __launch_bounds__(256) void attn_kernel(
    const bf16_t* __restrict__ q2a, const bf16_t* __restrict__ ka,
    const bf16_t* __restrict__ v1a, const bf16_t* __restrict__ v2Ta,
    const bf16_t* __restrict__ Wcb, const float* __restrict__ bc,
    const float* __restrict__ mask, float* __restrict__ out)
{
  __shared__ __align__(16) bf16_t pl[4][16 * NP];
  const int tid = threadIdx.x;
  const int w = tid >> 6, lane = tid & 63;
  const int g = lane >> 4, li = lane & 15;
  const int bh = blockIdx.x >> 1, half = blockIdx.x & 1;
  const int b = bh >> 3, h = bh & 7;
  const bf16_t* q2  = q2a  + (size_t)bh * MP * HD;
  const bf16_t* kk  = ka   + (size_t)bh * MP * HD;
  const bf16_t* v1  = v1a  + (size_t)bh * MP * HD;
  const bf16_t* v2T = v2Ta + (size_t)bh * HD * NP;
  const float* mb = mask + b * Mv;

  const int t_begin = half ? 7 : 0;
  const int t_end   = half ? 13 : 7;
  const f32x4 fzero = {};

  for (int mt = t_begin + w; mt < t_end; mt += 4) {
    // ---- QK^T ----
    bf16x8 aq[4];
#pragma unroll
    for (int ks = 0; ks < 4; ++ks)
      aq[ks] = *(const bf16x8*)(q2 + (size_t)(mt * 16 + li) * HD + ks * 32 + g * 8);

    f32x4 sacc[13];
#pragma unroll
    for (int nt = 0; nt < 13; ++nt) sacc[nt] = fzero;

    for (int nt = 0; nt < 13; ++nt) {
#pragma unroll
      for (int ks = 0; ks < 4; ++ks) {
        bf16x8 bk = *(const bf16x8*)(kk + (size_t)(nt * 16 + li) * HD + ks * 32 + g * 8);
        sacc[nt] = mfma_bf16(aq[ks], bk, sacc[nt]);
      }
    }

    // ---- masked softmax over n (rows m = g*4+q, cols nt*16+li) ----
    float mx[4]  = {-1e30f, -1e30f, -1e30f, -1e30f};
    float sum[4] = {0.f, 0.f, 0.f, 0.f};
#pragma unroll
    for (int nt = 0; nt < 13; ++nt) {
      const int col = nt * 16 + li;
      const bool valid = (col < Mv) && (mb[(col < Mv) ? col : 0] != 0.f);
#pragma unroll
      for (int q = 0; q < 4; ++q) {
        float s1 = sacc[nt][q] * 0.08838834764831845f;
        s1 = valid ? s1 : -1e9f;
        sacc[nt][q] = s1;
        mx[q] = fmaxf(mx[q], s1);
      }
    }
#pragma unroll
    for (int q = 0; q < 4; ++q)
#pragma unroll
      for (int msk = 1; msk < 16; msk <<= 1)
        mx[q] = fmaxf(mx[q], __shfl_xor(mx[q], msk, 64));

#pragma unroll
    for (int nt = 0; nt < 13; ++nt)
#pragma unroll
      for (int q = 0; q < 4; ++q) {
        const float e = expf(sacc[nt][q] - mx[q]);
        sacc[nt][q] = e;
        sum[q] += e;
      }
#pragma unroll
    for (int q = 0; q < 4; ++q) {
#pragma unroll
      for (int msk = 1; msk < 16; msk <<= 1)
        sum[q] += __shfl_xor(sum[q], msk, 64);
      sum[q] = 1.f / sum[q];
    }

    // ---- P -> LDS (bf16), rows = m-within-tile, cols = n ----
#pragma unroll
    for (int nt = 0; nt < 13; ++nt)
#pragma unroll
      for (int q = 0; q < 4; ++q)
        pl[w][(g * 4 + q) * NP + nt * 16 + li] = (bf16_t)(sacc[nt][q] * sum[q]);
#pragma unroll
    for (int q = 0; q < 4; ++q)       // zero pad cols [208,224)
      pl[w][(g * 4 + q) * NP + 208 + li] = (bf16_t)0.f;

    // ---- PV ----
    f32x4 oacc[8];
#pragma unroll
    for (int dt = 0; dt < 8; ++dt) oacc[dt] = fzero;
    for (int ks = 0; ks < 7; ++ks) {
      bf16x8 pa = *(const bf16x8*)(&pl[w][li * NP + ks * 32 + g * 8]);
#pragma unroll
      for (int dt = 0; dt < 8; ++dt) {
        bf16x8 bv = *(const bf16x8*)(v2T + (size_t)(dt * 16 + li) * NP + ks * 32 + g * 8);
        oacc[dt] = mfma_bf16(pa, bv, oacc[dt]);
      }
    }

    // ---- gate = sigmoid((v1 .* k) @ Wc^T + bc) ----
    f32x4 gacc[8];
#pragma unroll
    for (int et = 0; et < 8; ++et) gacc[et] = fzero;
    for (int ks = 0; ks < 4; ++ks) {
      bf16x8 a1 = *(const bf16x8*)(v1 + (size_t)(mt * 16 + li) * HD + ks * 32 + g * 8);
      bf16x8 a2 = *(const bf16x8*)(kk + (size_t)(mt * 16 + li) * HD + ks * 32 + g * 8);
      bf16x8 gi;
#pragma unroll
      for (int j = 0; j < 8; ++j) gi[j] = (bf16_t)((float)a1[j] * (float)a2[j]);
#pragma unroll
      for (int et = 0; et < 8; ++et) {
        bf16x8 bw = *(const bf16x8*)(Wcb + (size_t)(et * 16 + li) * HD + ks * 32 + g * 8);
        gacc[et] = mfma_bf16(gi, bw, gacc[et]);
      }
    }

    // ---- combine + store (f32, [b][m][h*128+col]) ----
#pragma unroll
    for (int dt = 0; dt < 8; ++dt) {
      const int col = dt * 16 + li;
      const float bcv = bc[col];
#pragma unroll
      for (int q = 0; q < 4; ++q) {
        const int m = mt * 16 + g * 4 + q;
        if (m < Mv) {
          const float gt = 1.f / (1.f + expf(-(gacc[dt][q] + bcv)));
          out[((size_t)(b * Mv + m)) * D + h * HD + col] = gt * oacc[dt][q];
        }
      }
    }
  }
}

// ---------------- residual + LayerNorm (writes f32 x and bf16 x) ----------------
__global__ __launch_bounds__(256) void ln_kernel(
    const float* __restrict__ xin, const float* __restrict__ attn,
    const float* __restrict__ wln, const float* __restrict__ bln,
    float* __restrict__ xout, bf16_t* __restrict__ xbout)
{
  const int row = blockIdx.x, t = threadIdx.x;
  const size_t base = (size_t)row * D + t * 4;
  float4 x4 = *(const float4*)(xin + base);
  float4 a4 = *(const float4*)(attn + base);
  float4 y = {x4.x + a4.x, x4.y + a4.y, x4.z + a4.z, x4.w + a4.w};
  float s  = y.x + y.y + y.z + y.w;
  float ss = y.x * y.x + y.y * y.y + y.z * y.z + y.w * y.w;
#pragma unroll
  for (int msk = 1; msk < 64; msk <<= 1) {
    s  += __shfl_xor(s,  msk, 64);
    ss += __shfl_xor(ss, msk, 64);
  }
  __shared__ float red[8];
  if ((t & 63) == 0) { red[(t >> 6) * 2] = s; red[(t >> 6) * 2 + 1] = ss; }
  __syncthreads();
  s  = red[0] + red[2] + red[4] + red[6];
  ss = red[1] + red[3] + red[5] + red[7];
  const float mean = s * (1.f / D);
  const float var  = ss * (1.f / D) - mean * mean;
  const float rs = rsqrtf(var + 1e-5f);
  float4 w4 = *(const float4*)(wln + t * 4);
  float4 b4 = *(const float4*)(bln + t * 4);
  float4 o = {(y.x - mean) * rs * w4.x + b4.x,
              (y.y - mean) * rs * w4.y + b4.y,
              (y.z - mean) * rs * w4.z + b4.z,
              (y.w - mean) * rs * w4.w + b4.w};
  *(float4*)(xout + base) = o;
  bf16x4 ob;
  ob[0] = (bf16_t)o.x; ob[1] = (bf16_t)o.y; ob[2] = (bf16_t)o.z; ob[3] = (bf16_t)o.w;
  *(bf16x4*)(xbout + base) = ob;
}

// ---------------- masked mean pool ----------------
__global__ __launch_bounds__(256) void gv_kernel(const float* __restrict__ x,
                                                 const float* __restrict__ mask,
                                                 float* __restrict__ gv) {
  const int b = blockIdx.x, t = threadIdx.x;
  float msum = 0.f;
  float4 acc = {0.f, 0.f, 0.f, 0.f};
  const float* mb = mask + b * Mv;
  const float* xp = x + (size_t)b * Mv * D + t * 4;
  for (int m = 0; m < Mv; ++m) {
    const float mv = mb[m];
    msum += mv;
    float4 x4 = *(const float4*)(xp + (size_t)m * D);
    acc.x += x4.x * mv; acc.y += x4.y * mv; acc.z += x4.z * mv; acc.w += x4.w * mv;
  }
  const float inv = 1.f / msum;
  float4 o = {acc.x * inv, acc.y * inv, acc.z * inv, acc.w * inv};
  *(float4*)(gv + (size_t)b * D + t * 4) = o;
}

extern "C" void kernel_launch(void* const* d_in, const int* in_sizes, int n_in,
                              void* d_out, int out_size, void* d_ws, size_t ws_size,
                              hipStream_t stream) {
  const float* att_feats = (const float*)d_in[0];
  const float* att_mask  = (const float*)d_in[1];
  const float* Wq2 = (const float*)d_in[2];
  const float* bq2 = (const float*)d_in[3];
  const float* gq2w = (const float*)d_in[4];
  const float* gq2b = (const float*)d_in[5];
  const float* Wk  = (const float*)d_in[6];
  const float* bk  = (const float*)d_in[7];
  const float* gkw = (const float*)d_in[8];
  const float* gkb = (const float*)d_in[9];
  const float* Wv1 = (const float*)d_in[10];
  const float* bv1 = (const float*)d_in[11];
  const float* gv1w = (const float*)d_in[12];
  const float* gv1b = (const float*)d_in[13];
  const float* Wv2 = (const float*)d_in[14];
  const float* bv2 = (const float*)d_in[15];
  const float* gv2w = (const float*)d_in[16];
  const float* gv2b = (const float*)d_in[17];
  const float* Wc  = (const float*)d_in[18];
  const float* bc  = (const float*)d_in[19];
  const float* lnw = (const float*)d_in[20];
  const float* lnb = (const float*)d_in[21];

  char* ws = (char*)d_ws;
  size_t off = 0;
  auto alloc = [&](size_t n) { char* p = ws + off; off += (n + 255) & ~(size_t)255; return p; };
  bf16_t* wW   = (bf16_t*)alloc(4ull * 3 * 1024 * 1024 * 2);
  bf16_t* wWc  = (bf16_t*)alloc(3ull * 128 * 128 * 2);
  bf16_t* xb   = (bf16_t*)alloc((size_t)BM * D * 2);
  float*  attn_o = (float*)alloc((size_t)BM * D * 4);
  bf16_t* q2p  = (bf16_t*)alloc((size_t)Bv * H * MP * HD * 2);
  bf16_t* kp   = (bf16_t*)alloc((size_t)Bv * H * MP * HD * 2);
  bf16_t* v1p  = (bf16_t*)alloc((size_t)Bv * H * MP * HD * 2);
  bf16_t* v2T  = (bf16_t*)alloc((size_t)Bv * H * HD * NP * 2);

  float* xf = (float*)d_out + (size_t)Bv * D;   // final/intermediate x lives in d_out

  // weight / input conversions (every launch: same work each call)
  cvt_kernel<<<1024, 256, 0, stream>>>(Wq2, wW + 0ull * 3 * 1024 * 1024, 3 * 1024 * 1024);
  cvt_kernel<<<1024, 256, 0, stream>>>(Wk,  wW + 1ull * 3 * 1024 * 1024, 3 * 1024 * 1024);
  cvt_kernel<<<1024, 256, 0, stream>>>(Wv1, wW + 2ull * 3 * 1024 * 1024, 3 * 1024 * 1024);
  cvt_kernel<<<1024, 256, 0, stream>>>(Wv2, wW + 3ull * 3 * 1024 * 1024, 3 * 1024 * 1024);
  cvt_kernel<<<64, 256, 0, stream>>>(Wc, wWc, 3 * 128 * 128);
  cvt_kernel<<<1024, 256, 0, stream>>>(att_feats, xb, BM * D);

  for (int i = 0; i < 3; ++i) {
    proj_kernel<<<dim3(49, 8, 4), 256, 0, stream>>>(
        xb, wW,
        bq2, bk, bv1, bv2,
        gq2w, gkw, gv1w, gv2w,
        gq2b, gkb, gv1b, gv2b,
        i, q2p, kp, v1p, v2T);
    attn_kernel<<<512, 256, 0, stream>>>(
        q2p, kp, v1p, v2T,
        wWc + (size_t)i * 128 * 128, bc + (size_t)i * 128,
        att_mask, attn_o);
    ln_kernel<<<BM, 256, 0, stream>>>(
        (i == 0) ? att_feats : xf, attn_o,
        lnw + (size_t)i * D, lnb + (size_t)i * D,
        xf, xb);
  }

  gv_kernel<<<Bv, 256, 0, stream>>>(xf, att_mask, (float*)d_out);
}

// Round 8
// 872.612 us; speedup vs baseline: 1.3610x; 1.3610x over previous
//
#include <hip/hip_runtime.h>
#include <cstdint>
#include <cstddef>

#define H 8
#define D 1024
#define HD 128
#define Bv 32
#define Mv 196
#define BM 6272      // Bv*Mv
#define MP 208       // padded token rows per (b,h)
#define NP 224       // padded cols for P / v2T (7*32)

typedef __bf16 bf16_t;
typedef __bf16 bf16x8 __attribute__((ext_vector_type(8)));
typedef __bf16 bf16x4 __attribute__((ext_vector_type(4)));
typedef float  f32x4  __attribute__((ext_vector_type(4)));

__device__ __forceinline__ void gl_lds16(const void* g, void* l) {
  __builtin_amdgcn_global_load_lds((const __attribute__((address_space(1))) void*)g,
                                   (__attribute__((address_space(3))) void*)l, 16, 0, 0);
}

__device__ __forceinline__ f32x4 mfma_bf16(bf16x8 a, bf16x8 b, f32x4 c) {
  return __builtin_amdgcn_mfma_f32_16x16x32_bf16(a, b, c, 0, 0, 0);
}

// ---------------- f32 -> bf16 convert ----------------
__global__ __launch_bounds__(256) void cvt_kernel(const float* __restrict__ s,
                                                  bf16_t* __restrict__ d, int n) {
  int i = (blockIdx.x * 256 + threadIdx.x) * 4;
  const int stride = gridDim.x * 256 * 4;
  for (; i < n; i += stride) {
    float4 v = *(const float4*)(s + i);
    bf16x4 o;
    o[0] = (bf16_t)v.x; o[1] = (bf16_t)v.y; o[2] = (bf16_t)v.z; o[3] = (bf16_t)v.w;
    *(bf16x4*)(d + i) = o;
  }
}

// ---------------- fused projection: GEMM + bias + CELU + per-head groupnorm ----------------
// grid 1568 linear; bijective remap: c = wg%8 (XCD), i = wg/8;
// nt = c*4 + (i&3)  (0..31 -> p = nt>>3, h = nt&7), rt = i>>2 (0..48).
// Each XCD owns 4 N-tiles (1 MB of W resident in its L2); A-tile reused 4x back-to-back.
__global__ __launch_bounds__(256) void proj_kernel(
    const bf16_t* __restrict__ Xb, const bf16_t* __restrict__ Wall,
    const float* __restrict__ b0, const float* __restrict__ b1,
    const float* __restrict__ b2, const float* __restrict__ b3,
    const float* __restrict__ w0, const float* __restrict__ w1,
    const float* __restrict__ w2, const float* __restrict__ w3,
    const float* __restrict__ c0, const float* __restrict__ c1,
    const float* __restrict__ c2, const float* __restrict__ c3,
    int layer,
    bf16_t* __restrict__ oq2, bf16_t* __restrict__ ok,
    bf16_t* __restrict__ ov1, bf16_t* __restrict__ ov2T)
{
  __shared__ __align__(16) char smem[32768 + 2048];
  bf16_t* lA = (bf16_t*)smem;             // [128][64]
  bf16_t* lB = (bf16_t*)(smem + 16384);   // [128][64]
  float*  red = (float*)(smem + 32768);   // [2][128][2]

  const int tid = threadIdx.x;
  const int w = tid >> 6, lane = tid & 63;
  const int g = lane >> 4, li = lane & 15;
  const int wr = w >> 1, wc = w & 1;

  const int wg = blockIdx.x;
  const int cX = wg & 7, ii = wg >> 3;
  const int nt = cX * 4 + (ii & 3);
  const int rt = ii >> 2;
  const int p = nt >> 3, h = nt & 7;
  const int row0 = rt * 128;

  const bf16_t* Wp = Wall + ((size_t)p * 3 + layer) * (1024u * 1024u) + (size_t)h * 128 * 1024;

  // staging: tile rows of 64 bf16 = 128B; thread t covers row=t>>3, 16B chunk (t&7); round j adds 32 rows
  const int srow = tid >> 3;
  const int scol = (tid & 7) * 8;       // element offset
  const bf16_t* gA = Xb + (size_t)(row0 + srow) * 1024 + scol;
  const bf16_t* gB = Wp + (size_t)srow * 1024 + scol;
  char* lAd = smem + tid * 16;
  char* lBd = smem + 16384 + tid * 16;

  f32x4 acc[4][4] = {};

  for (int kt = 0; kt < 16; ++kt) {
    const int k0 = kt * 64;
#pragma unroll
    for (int j = 0; j < 4; ++j)
      gl_lds16(gA + (size_t)j * 32 * 1024 + k0, lAd + j * 4096);
#pragma unroll
    for (int j = 0; j < 4; ++j)
      gl_lds16(gB + (size_t)j * 32 * 1024 + k0, lBd + j * 4096);
    __syncthreads();
    bf16x8 af[2][4], bfr[2][4];
#pragma unroll
    for (int ks = 0; ks < 2; ++ks) {
#pragma unroll
      for (int mi = 0; mi < 4; ++mi)
        af[ks][mi] = *(const bf16x8*)(lA + (wr * 64 + mi * 16 + li) * 64 + ks * 32 + g * 8);
#pragma unroll
      for (int ni = 0; ni < 4; ++ni)
        bfr[ks][ni] = *(const bf16x8*)(lB + (wc * 64 + ni * 16 + li) * 64 + ks * 32 + g * 8);
    }
#pragma unroll
    for (int ks = 0; ks < 2; ++ks)
#pragma unroll
      for (int mi = 0; mi < 4; ++mi)
#pragma unroll
        for (int ni = 0; ni < 4; ++ni)
          acc[mi][ni] = mfma_bf16(af[ks][mi], bfr[ks][ni], acc[mi][ni]);
    __syncthreads();
  }

  const float* bias = (p == 0 ? b0 : p == 1 ? b1 : p == 2 ? b2 : b3) + layer * 1024 + h * 128;
  const float* gwp  = (p == 0 ? w0 : p == 1 ? w1 : p == 2 ? w2 : w3) + layer * 1024 + h * 128;
  const float* gbp  = (p == 0 ? c0 : p == 1 ? c1 : p == 2 ? c2 : c3) + layer * 1024 + h * 128;

  float bia[4], gwv[4], gbv[4];
#pragma unroll
  for (int ni = 0; ni < 4; ++ni) {
    const int ct = wc * 64 + ni * 16 + li;
    bia[ni] = bias[ct]; gwv[ni] = gwp[ct]; gbv[ni] = gbp[ct];
  }

  // bias + CELU in place (alpha = 1.3); __expf-based, safe for very negative x
#pragma unroll
  for (int mi = 0; mi < 4; ++mi)
#pragma unroll
    for (int ni = 0; ni < 4; ++ni)
#pragma unroll
      for (int q = 0; q < 4; ++q) {
        float v = acc[mi][ni][q] + bia[ni];
        acc[mi][ni][q] = v > 0.f ? v : 1.3f * (__expf(v * (1.0f / 1.3f)) - 1.0f);
      }

  // per-row (per-head, 128 elems) stats: 16-lane reduce + cross-wc via LDS
#pragma unroll
  for (int mi = 0; mi < 4; ++mi)
#pragma unroll
    for (int q = 0; q < 4; ++q) {
      float s = 0.f, ss = 0.f;
#pragma unroll
      for (int ni = 0; ni < 4; ++ni) { float v = acc[mi][ni][q]; s += v; ss += v * v; }
#pragma unroll
      for (int msk = 1; msk < 16; msk <<= 1) {
        s  += __shfl_xor(s,  msk, 64);
        ss += __shfl_xor(ss, msk, 64);
      }
      if (li == 0) {
        const int row = wr * 64 + mi * 16 + g * 4 + q;
        red[(wc * 128 + row) * 2 + 0] = s;
        red[(wc * 128 + row) * 2 + 1] = ss;
      }
    }
  __syncthreads();

#pragma unroll
  for (int mi = 0; mi < 4; ++mi)
#pragma unroll
    for (int q = 0; q < 4; ++q) {
      const int row = wr * 64 + mi * 16 + g * 4 + q;
      const float s  = red[row * 2]     + red[(128 + row) * 2];
      const float ss = red[row * 2 + 1] + red[(128 + row) * 2 + 1];
      const float mean = s * (1.f / 128.f);
      const float var  = ss * (1.f / 128.f) - mean * mean;
      const float rs = rsqrtf(var + 1e-5f);
      const int rg = row0 + row;
      const int bb = rg / 196;
      const int mm = rg - bb * 196;
      const size_t bh = (size_t)(bb * 8 + h);
#pragma unroll
      for (int ni = 0; ni < 4; ++ni) {
        const int ct = wc * 64 + ni * 16 + li;
        const float o = (acc[mi][ni][q] - mean) * rs * gwv[ni] + gbv[ni];
        const bf16_t ob = (bf16_t)o;
        if (p == 0)      oq2[(bh * MP + mm) * HD + ct] = ob;
        else if (p == 1) ok [(bh * MP + mm) * HD + ct] = ob;
        else if (p == 2) ov1[(bh * MP + mm) * HD + ct] = ob;
        else             ov2T[(bh * HD + ct) * NP + mm] = ob;   // transposed for PV B-operand
      }
    }
}

// ---------------- attention + gate ----------------
// grid (256, 13): blockIdx.x = bh, blockIdx.y = m-tile; ONE wave per block (64 thr).
__global__ __launch_bounds__(64) void attn_kernel(
    const bf16_t* __restrict__ q2a, const bf16_t* __restrict__ ka,
    const bf16_t* __restrict__ v1a, const bf16_t* __restrict__ v2Ta,
    const bf16_t* __restrict__ Wcb, const float* __restrict__ bc,
    const float* __restrict__ mask, float* __restrict__ out)
{
  __shared__ __align__(16) bf16_t pl[16 * NP];
  const int lane = threadIdx.x;
  const int g = lane >> 4, li = lane & 15;
  const int bh = blockIdx.x;
  const int mt = blockIdx.y;
  const int b = bh >> 3, h = bh & 7;
  const bf16_t* q2  = q2a  + (size_t)bh * MP * HD;
  const bf16_t* kk  = ka   + (size_t)bh * MP * HD;
  const bf16_t* v1  = v1a  + (size_t)bh * MP * HD;
  const bf16_t* v2T = v2Ta + (size_t)bh * HD * NP;
  const float* mb = mask + b * Mv;
  const f32x4 fzero = {};

  // ---- QK^T ----
  bf16x8 aq[4];
#pragma unroll
  for (int ks = 0; ks < 4; ++ks)
    aq[ks] = *(const bf16x8*)(q2 + (size_t)(mt * 16 + li) * HD + ks * 32 + g * 8);

  f32x4 sacc[13];
#pragma unroll
  for (int nt = 0; nt < 13; ++nt) sacc[nt] = fzero;

  for (int nt = 0; nt < 13; ++nt) {
#pragma unroll
    for (int ks = 0; ks < 4; ++ks) {
      bf16x8 bk = *(const bf16x8*)(kk + (size_t)(nt * 16 + li) * HD + ks * 32 + g * 8);
      sacc[nt] = mfma_bf16(aq[ks], bk, sacc[nt]);
    }
  }

  // ---- masked softmax (rows m = g*4+q, cols nt*16+li) ----
  float mx[4]  = {-1e30f, -1e30f, -1e30f, -1e30f};
  float sum[4] = {0.f, 0.f, 0.f, 0.f};
#pragma unroll
  for (int nt = 0; nt < 13; ++nt) {
    const int col = nt * 16 + li;
    const bool valid = (col < Mv) && (mb[(col < Mv) ? col : 0] != 0.f);
#pragma unroll
    for (int q = 0; q < 4; ++q) {
      float s1 = sacc[nt][q] * 0.08838834764831845f;
      s1 = valid ? s1 : -1e9f;
      sacc[nt][q] = s1;
      mx[q] = fmaxf(mx[q], s1);
    }
  }
#pragma unroll
  for (int q = 0; q < 4; ++q)
#pragma unroll
    for (int msk = 1; msk < 16; msk <<= 1)
      mx[q] = fmaxf(mx[q], __shfl_xor(mx[q], msk, 64));

#pragma unroll
  for (int nt = 0; nt < 13; ++nt)
#pragma unroll
    for (int q = 0; q < 4; ++q) {
      const float e = __expf(sacc[nt][q] - mx[q]);
      sacc[nt][q] = e;
      sum[q] += e;
    }
#pragma unroll
  for (int q = 0; q < 4; ++q) {
#pragma unroll
    for (int msk = 1; msk < 16; msk <<= 1)
      sum[q] += __shfl_xor(sum[q], msk, 64);
    sum[q] = 1.f / sum[q];
  }

  // ---- P -> LDS (bf16) ----
#pragma unroll
  for (int nt = 0; nt < 13; ++nt)
#pragma unroll
    for (int q = 0; q < 4; ++q)
      pl[(g * 4 + q) * NP + nt * 16 + li] = (bf16_t)(sacc[nt][q] * sum[q]);
#pragma unroll
  for (int q = 0; q < 4; ++q)       // zero pad cols [208,224)
    pl[(g * 4 + q) * NP + 208 + li] = (bf16_t)0.f;

  // ---- PV ----
  f32x4 oacc[8];
#pragma unroll
  for (int dt = 0; dt < 8; ++dt) oacc[dt] = fzero;
  for (int ks = 0; ks < 7; ++ks) {
    bf16x8 pa = *(const bf16x8*)(&pl[li * NP + ks * 32 + g * 8]);
#pragma unroll
    for (int dt = 0; dt < 8; ++dt) {
      bf16x8 bv = *(const bf16x8*)(v2T + (size_t)(dt * 16 + li) * NP + ks * 32 + g * 8);
      oacc[dt] = mfma_bf16(pa, bv, oacc[dt]);
    }
  }

  // ---- gate = sigmoid((v1 .* k) @ Wc^T + bc) ----
  f32x4 gacc[8];
#pragma unroll
  for (int et = 0; et < 8; ++et) gacc[et] = fzero;
  for (int ks = 0; ks < 4; ++ks) {
    bf16x8 a1 = *(const bf16x8*)(v1 + (size_t)(mt * 16 + li) * HD + ks * 32 + g * 8);
    bf16x8 a2 = *(const bf16x8*)(kk + (size_t)(mt * 16 + li) * HD + ks * 32 + g * 8);
    bf16x8 gi;
#pragma unroll
    for (int j = 0; j < 8; ++j) gi[j] = (bf16_t)((float)a1[j] * (float)a2[j]);
#pragma unroll
    for (int et = 0; et < 8; ++et) {
      bf16x8 bw = *(const bf16x8*)(Wcb + (size_t)(et * 16 + li) * HD + ks * 32 + g * 8);
      gacc[et] = mfma_bf16(gi, bw, gacc[et]);
    }
  }

  // ---- combine + store ----
#pragma unroll
  for (int dt = 0; dt < 8; ++dt) {
    const int col = dt * 16 + li;
    const float bcv = bc[col];
#pragma unroll
    for (int q = 0; q < 4; ++q) {
      const int m = mt * 16 + g * 4 + q;
      if (m < Mv) {
        const float gt = 1.f / (1.f + __expf(-(gacc[dt][q] + bcv)));
        out[((size_t)(b * Mv + m)) * D + h * HD + col] = gt * oacc[dt][q];
      }
    }
  }
}

// ---------------- residual + LayerNorm (writes f32 x and bf16 x) ----------------
__global__ __launch_bounds__(256) void ln_kernel(
    const float* __restrict__ xin, const float* __restrict__ attn,
    const float* __restrict__ wln, const float* __restrict__ bln,
    float* __restrict__ xout, bf16_t* __restrict__ xbout)
{
  const int row = blockIdx.x, t = threadIdx.x;
  const size_t base = (size_t)row * D + t * 4;
  float4 x4 = *(const float4*)(xin + base);
  float4 a4 = *(const float4*)(attn + base);
  float4 y = {x4.x + a4.x, x4.y + a4.y, x4.z + a4.z, x4.w + a4.w};
  float s  = y.x + y.y + y.z + y.w;
  float ss = y.x * y.x + y.y * y.y + y.z * y.z + y.w * y.w;
#pragma unroll
  for (int msk = 1; msk < 64; msk <<= 1) {
    s  += __shfl_xor(s,  msk, 64);
    ss += __shfl_xor(ss, msk, 64);
  }
  __shared__ float red[8];
  if ((t & 63) == 0) { red[(t >> 6) * 2] = s; red[(t >> 6) * 2 + 1] = ss; }
  __syncthreads();
  s  = red[0] + red[2] + red[4] + red[6];
  ss = red[1] + red[3] + red[5] + red[7];
  const float mean = s * (1.f / D);
  const float var  = ss * (1.f / D) - mean * mean;
  const float rs = rsqrtf(var + 1e-5f);
  float4 w4 = *(const float4*)(wln + t * 4);
  float4 b4 = *(const float4*)(bln + t * 4);
  float4 o = {(y.x - mean) * rs * w4.x + b4.x,
              (y.y - mean) * rs * w4.y + b4.y,
              (y.z - mean) * rs * w4.z + b4.z,
              (y.w - mean) * rs * w4.w + b4.w};
  *(float4*)(xout + base) = o;
  bf16x4 ob;
  ob[0] = (bf16_t)o.x; ob[1] = (bf16_t)o.y; ob[2] = (bf16_t)o.z; ob[3] = (bf16_t)o.w;
  *(bf16x4*)(xbout + base) = ob;
}

// ---------------- masked mean pool ----------------
// grid (32, 4) x 256: thread owns one column; coalesced 1KB/instr loads.
__global__ __launch_bounds__(256) void gv_kernel(const float* __restrict__ x,
                                                 const float* __restrict__ mask,
                                                 float* __restrict__ gv) {
  const int b = blockIdx.x;
  const int col = blockIdx.y * 256 + threadIdx.x;
  const float* mb = mask + b * Mv;
  const float* xp = x + (size_t)b * Mv * D + col;
  float msum = 0.f, acc = 0.f;
  for (int m = 0; m < Mv; ++m) {
    const float mv = mb[m];
    msum += mv;
    acc += xp[(size_t)m * D] * mv;
  }
  gv[(size_t)b * D + col] = acc / msum;
}

extern "C" void kernel_launch(void* const* d_in, const int* in_sizes, int n_in,
                              void* d_out, int out_size, void* d_ws, size_t ws_size,
                              hipStream_t stream) {
  const float* att_feats = (const float*)d_in[0];
  const float* att_mask  = (const float*)d_in[1];
  const float* Wq2 = (const float*)d_in[2];
  const float* bq2 = (const float*)d_in[3];
  const float* gq2w = (const float*)d_in[4];
  const float* gq2b = (const float*)d_in[5];
  const float* Wk  = (const float*)d_in[6];
  const float* bk  = (const float*)d_in[7];
  const float* gkw = (const float*)d_in[8];
  const float* gkb = (const float*)d_in[9];
  const float* Wv1 = (const float*)d_in[10];
  const float* bv1 = (const float*)d_in[11];
  const float* gv1w = (const float*)d_in[12];
  const float* gv1b = (const float*)d_in[13];
  const float* Wv2 = (const float*)d_in[14];
  const float* bv2 = (const float*)d_in[15];
  const float* gv2w = (const float*)d_in[16];
  const float* gv2b = (const float*)d_in[17];
  const float* Wc  = (const float*)d_in[18];
  const float* bc  = (const float*)d_in[19];
  const float* lnw = (const float*)d_in[20];
  const float* lnb = (const float*)d_in[21];

  char* ws = (char*)d_ws;
  size_t off = 0;
  auto alloc = [&](size_t n) { char* p = ws + off; off += (n + 255) & ~(size_t)255; return p; };
  bf16_t* wW   = (bf16_t*)alloc(4ull * 3 * 1024 * 1024 * 2);
  bf16_t* wWc  = (bf16_t*)alloc(3ull * 128 * 128 * 2);
  bf16_t* xb   = (bf16_t*)alloc((size_t)BM * D * 2);
  float*  attn_o = (float*)alloc((size_t)BM * D * 4);
  bf16_t* q2p  = (bf16_t*)alloc((size_t)Bv * H * MP * HD * 2);
  bf16_t* kp   = (bf16_t*)alloc((size_t)Bv * H * MP * HD * 2);
  bf16_t* v1p  = (bf16_t*)alloc((size_t)Bv * H * MP * HD * 2);
  bf16_t* v2T  = (bf16_t*)alloc((size_t)Bv * H * HD * NP * 2);

  float* xf = (float*)d_out + (size_t)Bv * D;   // final/intermediate x lives in d_out

  cvt_kernel<<<1024, 256, 0, stream>>>(Wq2, wW + 0ull * 3 * 1024 * 1024, 3 * 1024 * 1024);
  cvt_kernel<<<1024, 256, 0, stream>>>(Wk,  wW + 1ull * 3 * 1024 * 1024, 3 * 1024 * 1024);
  cvt_kernel<<<1024, 256, 0, stream>>>(Wv1, wW + 2ull * 3 * 1024 * 1024, 3 * 1024 * 1024);
  cvt_kernel<<<1024, 256, 0, stream>>>(Wv2, wW + 3ull * 3 * 1024 * 1024, 3 * 1024 * 1024);
  cvt_kernel<<<64, 256, 0, stream>>>(Wc, wWc, 3 * 128 * 128);
  cvt_kernel<<<1024, 256, 0, stream>>>(att_feats, xb, BM * D);

  for (int i = 0; i < 3; ++i) {
    proj_kernel<<<1568, 256, 0, stream>>>(
        xb, wW,
        bq2, bk, bv1, bv2,
        gq2w, gkw, gv1w, gv2w,
        gq2b, gkb, gv1b, gv2b,
        i, q2p, kp, v1p, v2T);
    attn_kernel<<<dim3(256, 13), 64, 0, stream>>>(
        q2p, kp, v1p, v2T,
        wWc + (size_t)i * 128 * 128, bc + (size_t)i * 128,
        att_mask, attn_o);
    ln_kernel<<<BM, 256, 0, stream>>>(
        (i == 0) ? att_feats : xf, attn_o,
        lnw + (size_t)i * D, lnb + (size_t)i * D,
        xf, xb);
  }

  gv_kernel<<<dim3(Bv, 4), 256, 0, stream>>>(xf, att_mask, (float*)d_out);
}

// Round 12
// 834.622 us; speedup vs baseline: 1.4230x; 1.0455x over previous
//
#include <hip/hip_runtime.h>
#include <cstdint>
#include <cstddef>

#define H 8
#define D 1024
#define HD 128
#define Bv 32
#define Mv 196
#define BM 6272      // Bv*Mv
#define MP 208       // padded token rows per (b,h)
#define NP 224       // padded cols for P / v2T (7*32)

typedef __bf16 bf16_t;
typedef __bf16 bf16x8 __attribute__((ext_vector_type(8)));
typedef __bf16 bf16x4 __attribute__((ext_vector_type(4)));
typedef float  f32x4  __attribute__((ext_vector_type(4)));

__device__ __forceinline__ void gl_lds16(const void* g, void* l) {
  __builtin_amdgcn_global_load_lds((const __attribute__((address_space(1))) void*)g,
                                   (__attribute__((address_space(3))) void*)l, 16, 0, 0);
}

__device__ __forceinline__ f32x4 mfma_bf16(bf16x8 a, bf16x8 b, f32x4 c) {
  return __builtin_amdgcn_mfma_f32_16x16x32_bf16(a, b, c, 0, 0, 0);
}

// ---------------- f32 -> bf16 convert ----------------
__global__ __launch_bounds__(256) void cvt_kernel(const float* __restrict__ s,
                                                  bf16_t* __restrict__ d, int n) {
  int i = (blockIdx.x * 256 + threadIdx.x) * 4;
  const int stride = gridDim.x * 256 * 4;
  for (; i < n; i += stride) {
    float4 v = *(const float4*)(s + i);
    bf16x4 o;
    o[0] = (bf16_t)v.x; o[1] = (bf16_t)v.y; o[2] = (bf16_t)v.z; o[3] = (bf16_t)v.w;
    *(bf16x4*)(d + i) = o;
  }
}

// ---------------- fused projection: GEMM + bias + CELU + per-head groupnorm ----------------
// grid 1568 linear; bijective remap: c = wg%8 (XCD), i = wg/8;
// nt = c*4 + (i&3), rt = i>>2. Each XCD owns 4 N-tiles (W L2-resident; FETCH 65MB, R8).
// LDS tiles [128][64] bf16, row stride 128B. T2 XOR-swizzle (rule #21: both sides):
//   staging: global source chunk = (tid&7) ^ (srow&7)   (gload_lds writes LDS linearly)
//   read:    chunk = (ks*4+g) ^ (li&7)                  (row&7 == li&7 for all mi/ni)
// Kills the 16-way bank conflict of R8 (19.3M/dispatch).
__global__ __launch_bounds__(256) void proj_kernel(
    const bf16_t* __restrict__ Xb, const bf16_t* __restrict__ Wall,
    const float* __restrict__ b0, const float* __restrict__ b1,
    const float* __restrict__ b2, const float* __restrict__ b3,
    const float* __restrict__ w0, const float* __restrict__ w1,
    const float* __restrict__ w2, const float* __restrict__ w3,
    const float* __restrict__ c0, const float* __restrict__ c1,
    const float* __restrict__ c2, const float* __restrict__ c3,
    int layer,
    bf16_t* __restrict__ oq2, bf16_t* __restrict__ ok,
    bf16_t* __restrict__ ov1, bf16_t* __restrict__ ov2T)
{
  __shared__ __align__(16) char smem[32768 + 2048];
  bf16_t* lA = (bf16_t*)smem;             // [128][64]
  bf16_t* lB = (bf16_t*)(smem + 16384);   // [128][64]
  float*  red = (float*)(smem + 32768);   // [2][128][2]

  const int tid = threadIdx.x;
  const int w = tid >> 6, lane = tid & 63;
  const int g = lane >> 4, li = lane & 15;
  const int wr = w >> 1, wc = w & 1;
  const int sw = li & 7;                  // read-side XOR (row&7 == li&7)

  const int wg = blockIdx.x;
  const int cX = wg & 7, ii = wg >> 3;
  const int nt = cX * 4 + (ii & 3);
  const int rt = ii >> 2;
  const int p = nt >> 3, h = nt & 7;
  const int row0 = rt * 128;

  const bf16_t* Wp = Wall + ((size_t)p * 3 + layer) * (1024u * 1024u) + (size_t)h * 128 * 1024;

  // staging: row = tid>>3 (+32 per j), 16B chunk = (tid&7) XOR (row&7); LDS dest linear.
  const int srow = tid >> 3;
  const int schunk = (tid & 7) ^ (srow & 7);
  const bf16_t* gA = Xb + (size_t)(row0 + srow) * 1024 + schunk * 8;
  const bf16_t* gB = Wp + (size_t)srow * 1024 + schunk * 8;
  char* lAd = smem + tid * 16;
  char* lBd = smem + 16384 + tid * 16;

  f32x4 acc[4][4] = {};

  for (int kt = 0; kt < 16; ++kt) {
    const int k0 = kt * 64;
#pragma unroll
    for (int j = 0; j < 4; ++j)
      gl_lds16(gA + (size_t)j * 32 * 1024 + k0, lAd + j * 4096);
#pragma unroll
    for (int j = 0; j < 4; ++j)
      gl_lds16(gB + (size_t)j * 32 * 1024 + k0, lBd + j * 4096);
    __syncthreads();
    bf16x8 af[2][4], bfr[2][4];
#pragma unroll
    for (int ks = 0; ks < 2; ++ks) {
#pragma unroll
      for (int mi = 0; mi < 4; ++mi)
        af[ks][mi] = *(const bf16x8*)(lA + (wr * 64 + mi * 16 + li) * 64
                                         + (((ks * 4 + g) ^ sw) * 8));
#pragma unroll
      for (int ni = 0; ni < 4; ++ni)
        bfr[ks][ni] = *(const bf16x8*)(lB + (wc * 64 + ni * 16 + li) * 64
                                          + (((ks * 4 + g) ^ sw) * 8));
    }
#pragma unroll
    for (int ks = 0; ks < 2; ++ks)
#pragma unroll
      for (int mi = 0; mi < 4; ++mi)
#pragma unroll
        for (int ni = 0; ni < 4; ++ni)
          acc[mi][ni] = mfma_bf16(af[ks][mi], bfr[ks][ni], acc[mi][ni]);
    __syncthreads();
  }

  const float* bias = (p == 0 ? b0 : p == 1 ? b1 : p == 2 ? b2 : b3) + layer * 1024 + h * 128;
  const float* gwp  = (p == 0 ? w0 : p == 1 ? w1 : p == 2 ? w2 : w3) + layer * 1024 + h * 128;
  const float* gbp  = (p == 0 ? c0 : p == 1 ? c1 : p == 2 ? c2 : c3) + layer * 1024 + h * 128;

  float bia[4], gwv[4], gbv[4];
#pragma unroll
  for (int ni = 0; ni < 4; ++ni) {
    const int ct = wc * 64 + ni * 16 + li;
    bia[ni] = bias[ct]; gwv[ni] = gwp[ct]; gbv[ni] = gbp[ct];
  }

  // bias + CELU in place (alpha = 1.3)
#pragma unroll
  for (int mi = 0; mi < 4; ++mi)
#pragma unroll
    for (int ni = 0; ni < 4; ++ni)
#pragma unroll
      for (int q = 0; q < 4; ++q) {
        float v = acc[mi][ni][q] + bia[ni];
        acc[mi][ni][q] = v > 0.f ? v : 1.3f * (__expf(v * (1.0f / 1.3f)) - 1.0f);
      }

  // per-row (per-head, 128 elems) stats: 16-lane reduce + cross-wc via LDS
#pragma unroll
  for (int mi = 0; mi < 4; ++mi)
#pragma unroll
    for (int q = 0; q < 4; ++q) {
      float s = 0.f, ss = 0.f;
#pragma unroll
      for (int ni = 0; ni < 4; ++ni) { float v = acc[mi][ni][q]; s += v; ss += v * v; }
#pragma unroll
      for (int msk = 1; msk < 16; msk <<= 1) {
        s  += __shfl_xor(s,  msk, 64);
        ss += __shfl_xor(ss, msk, 64);
      }
      if (li == 0) {
        const int row = wr * 64 + mi * 16 + g * 4 + q;
        red[(wc * 128 + row) * 2 + 0] = s;
        red[(wc * 128 + row) * 2 + 1] = ss;
      }
    }
  __syncthreads();

#pragma unroll
  for (int mi = 0; mi < 4; ++mi)
#pragma unroll
    for (int q = 0; q < 4; ++q) {
      const int row = wr * 64 + mi * 16 + g * 4 + q;
      const float s  = red[row * 2]     + red[(128 + row) * 2];
      const float ss = red[row * 2 + 1] + red[(128 + row) * 2 + 1];
      const float mean = s * (1.f / 128.f);
      const float var  = ss * (1.f / 128.f) - mean * mean;
      const float rs = rsqrtf(var + 1e-5f);
      const int rg = row0 + row;
      const int bb = rg / 196;
      const int mm = rg - bb * 196;
      const size_t bh = (size_t)(bb * 8 + h);
#pragma unroll
      for (int ni = 0; ni < 4; ++ni) {
        const int ct = wc * 64 + ni * 16 + li;
        const float o = (acc[mi][ni][q] - mean) * rs * gwv[ni] + gbv[ni];
        const bf16_t ob = (bf16_t)o;
        if (p == 0)      oq2[(bh * MP + mm) * HD + ct] = ob;
        else if (p == 1) ok [(bh * MP + mm) * HD + ct] = ob;
        else if (p == 2) ov1[(bh * MP + mm) * HD + ct] = ob;
        else             ov2T[(bh * HD + ct) * NP + mm] = ob;   // transposed for PV B-operand
      }
    }
}

// ---------------- attention + gate ----------------
// grid (256, 13): blockIdx.x = bh, blockIdx.y = m-tile; ONE wave per block (64 thr).
__global__ __launch_bounds__(64) void attn_kernel(
    const bf16_t* __restrict__ q2a, const bf16_t* __restrict__ ka,
    const bf16_t* __restrict__ v1a, const bf16_t* __restrict__ v2Ta,
    const bf16_t* __restrict__ Wcb, const float* __restrict__ bc,
    const float* __restrict__ mask, float* __restrict__ out)
{
  __shared__ __align__(16) bf16_t pl[16 * NP];
  const int lane = threadIdx.x;
  const int g = lane >> 4, li = lane & 15;
  const int bh = blockIdx.x;
  const int mt = blockIdx.y;
  const int b = bh >> 3, h = bh & 7;
  const bf16_t* q2  = q2a  + (size_t)bh * MP * HD;
  const bf16_t* kk  = ka   + (size_t)bh * MP * HD;
  const bf16_t* v1  = v1a  + (size_t)bh * MP * HD;
  const bf16_t* v2T = v2Ta + (size_t)bh * HD * NP;
  const float* mb = mask + b * Mv;
  const f32x4 fzero = {};

  // ---- QK^T ----
  bf16x8 aq[4];
#pragma unroll
  for (int ks = 0; ks < 4; ++ks)
    aq[ks] = *(const bf16x8*)(q2 + (size_t)(mt * 16 + li) * HD + ks * 32 + g * 8);

  f32x4 sacc[13];
#pragma unroll
  for (int nt = 0; nt < 13; ++nt) sacc[nt] = fzero;

  for (int nt = 0; nt < 13; ++nt) {
#pragma unroll
    for (int ks = 0; ks < 4; ++ks) {
      bf16x8 bk = *(const bf16x8*)(kk + (size_t)(nt * 16 + li) * HD + ks * 32 + g * 8);
      sacc[nt] = mfma_bf16(aq[ks], bk, sacc[nt]);
    }
  }

  // ---- masked softmax (rows m = g*4+q, cols nt*16+li) ----
  float mx[4]  = {-1e30f, -1e30f, -1e30f, -1e30f};
  float sum[4] = {0.f, 0.f, 0.f, 0.f};
#pragma unroll
  for (int nt = 0; nt < 13; ++nt) {
    const int col = nt * 16 + li;
    const bool valid = (col < Mv) && (mb[(col < Mv) ? col : 0] != 0.f);
#pragma unroll
    for (int q = 0; q < 4; ++q) {
      float s1 = sacc[nt][q] * 0.08838834764831845f;
      s1 = valid ? s1 : -1e9f;
      sacc[nt][q] = s1;
      mx[q] = fmaxf(mx[q], s1);
    }
  }
#pragma unroll
  for (int q = 0; q < 4; ++q)
#pragma unroll
    for (int msk = 1; msk < 16; msk <<= 1)
      mx[q] = fmaxf(mx[q], __shfl_xor(mx[q], msk, 64));

#pragma unroll
  for (int nt = 0; nt < 13; ++nt)
#pragma unroll
    for (int q = 0; q < 4; ++q) {
      const float e = __expf(sacc[nt][q] - mx[q]);
      sacc[nt][q] = e;
      sum[q] += e;
    }
#pragma unroll
  for (int q = 0; q < 4; ++q) {
#pragma unroll
    for (int msk = 1; msk < 16; msk <<= 1)
      sum[q] += __shfl_xor(sum[q], msk, 64);
    sum[q] = 1.f / sum[q];
  }

  // ---- P -> LDS (bf16) ----
#pragma unroll
  for (int nt = 0; nt < 13; ++nt)
#pragma unroll
    for (int q = 0; q < 4; ++q)
      pl[(g * 4 + q) * NP + nt * 16 + li] = (bf16_t)(sacc[nt][q] * sum[q]);
#pragma unroll
  for (int q = 0; q < 4; ++q)       // zero pad cols [208,224)
    pl[(g * 4 + q) * NP + 208 + li] = (bf16_t)0.f;

  // ---- PV ----
  f32x4 oacc[8];
#pragma unroll
  for (int dt = 0; dt < 8; ++dt) oacc[dt] = fzero;
  for (int ks = 0; ks < 7; ++ks) {
    bf16x8 pa = *(const bf16x8*)(&pl[li * NP + ks * 32 + g * 8]);
#pragma unroll
    for (int dt = 0; dt < 8; ++dt) {
      bf16x8 bv = *(const bf16x8*)(v2T + (size_t)(dt * 16 + li) * NP + ks * 32 + g * 8);
      oacc[dt] = mfma_bf16(pa, bv, oacc[dt]);
    }
  }

  // ---- gate = sigmoid((v1 .* k) @ Wc^T + bc) ----
  f32x4 gacc[8];
#pragma unroll
  for (int et = 0; et < 8; ++et) gacc[et] = fzero;
  for (int ks = 0; ks < 4; ++ks) {
    bf16x8 a1 = *(const bf16x8*)(v1 + (size_t)(mt * 16 + li) * HD + ks * 32 + g * 8);
    bf16x8 a2 = *(const bf16x8*)(kk + (size_t)(mt * 16 + li) * HD + ks * 32 + g * 8);
    bf16x8 gi;
#pragma unroll
    for (int j = 0; j < 8; ++j) gi[j] = (bf16_t)((float)a1[j] * (float)a2[j]);
#pragma unroll
    for (int et = 0; et < 8; ++et) {
      bf16x8 bw = *(const bf16x8*)(Wcb + (size_t)(et * 16 + li) * HD + ks * 32 + g * 8);
      gacc[et] = mfma_bf16(gi, bw, gacc[et]);
    }
  }

  // ---- combine + store ----
#pragma unroll
  for (int dt = 0; dt < 8; ++dt) {
    const int col = dt * 16 + li;
    const float bcv = bc[col];
#pragma unroll
    for (int q = 0; q < 4; ++q) {
      const int m = mt * 16 + g * 4 + q;
      if (m < Mv) {
        const float gt = 1.f / (1.f + __expf(-(gacc[dt][q] + bcv)));
        out[((size_t)(b * Mv + m)) * D + h * HD + col] = gt * oacc[dt][q];
      }
    }
  }
}

// ---------------- residual + LayerNorm (writes f32 x and bf16 x) ----------------
__global__ __launch_bounds__(256) void ln_kernel(
    const float* __restrict__ xin, const float* __restrict__ attn,
    const float* __restrict__ wln, const float* __restrict__ bln,
    float* __restrict__ xout, bf16_t* __restrict__ xbout)
{
  const int row = blockIdx.x, t = threadIdx.x;
  const size_t base = (size_t)row * D + t * 4;
  float4 x4 = *(const float4*)(xin + base);
  float4 a4 = *(const float4*)(attn + base);
  float4 y = {x4.x + a4.x, x4.y + a4.y, x4.z + a4.z, x4.w + a4.w};
  float s  = y.x + y.y + y.z + y.w;
  float ss = y.x * y.x + y.y * y.y + y.z * y.z + y.w * y.w;
#pragma unroll
  for (int msk = 1; msk < 64; msk <<= 1) {
    s  += __shfl_xor(s,  msk, 64);
    ss += __shfl_xor(ss, msk, 64);
  }
  __shared__ float red[8];
  if ((t & 63) == 0) { red[(t >> 6) * 2] = s; red[(t >> 6) * 2 + 1] = ss; }
  __syncthreads();
  s  = red[0] + red[2] + red[4] + red[6];
  ss = red[1] + red[3] + red[5] + red[7];
  const float mean = s * (1.f / D);
  const float var  = ss * (1.f / D) - mean * mean;
  const float rs = rsqrtf(var + 1e-5f);
  float4 w4 = *(const float4*)(wln + t * 4);
  float4 b4 = *(const float4*)(bln + t * 4);
  float4 o = {(y.x - mean) * rs * w4.x + b4.x,
              (y.y - mean) * rs * w4.y + b4.y,
              (y.z - mean) * rs * w4.z + b4.z,
              (y.w - mean) * rs * w4.w + b4.w};
  *(float4*)(xout + base) = o;
  bf16x4 ob;
  ob[0] = (bf16_t)o.x; ob[1] = (bf16_t)o.y; ob[2] = (bf16_t)o.z; ob[3] = (bf16_t)o.w;
  *(bf16x4*)(xbout + base) = ob;
}

// ---------------- masked mean pool ----------------
// grid (32, 4) x 256: thread owns one column; coalesced 1KB/instr loads.
__global__ __launch_bounds__(256) void gv_kernel(const float* __restrict__ x,
                                                 const float* __restrict__ mask,
                                                 float* __restrict__ gv) {
  const int b = blockIdx.x;
  const int col = blockIdx.y * 256 + threadIdx.x;
  const float* mb = mask + b * Mv;
  const float* xp = x + (size_t)b * Mv * D + col;
  float msum = 0.f, acc = 0.f;
  for (int m = 0; m < Mv; ++m) {
    const float mv = mb[m];
    msum += mv;
    acc += xp[(size_t)m * D] * mv;
  }
  gv[(size_t)b * D + col] = acc / msum;
}

extern "C" void kernel_launch(void* const* d_in, const int* in_sizes, int n_in,
                              void* d_out, int out_size, void* d_ws, size_t ws_size,
                              hipStream_t stream) {
  const float* att_feats = (const float*)d_in[0];
  const float* att_mask  = (const float*)d_in[1];
  const float* Wq2 = (const float*)d_in[2];
  const float* bq2 = (const float*)d_in[3];
  const float* gq2w = (const float*)d_in[4];
  const float* gq2b = (const float*)d_in[5];
  const float* Wk  = (const float*)d_in[6];
  const float* bk  = (const float*)d_in[7];
  const float* gkw = (const float*)d_in[8];
  const float* gkb = (const float*)d_in[9];
  const float* Wv1 = (const float*)d_in[10];
  const float* bv1 = (const float*)d_in[11];
  const float* gv1w = (const float*)d_in[12];
  const float* gv1b = (const float*)d_in[13];
  const float* Wv2 = (const float*)d_in[14];
  const float* bv2 = (const float*)d_in[15];
  const float* gv2w = (const float*)d_in[16];
  const float* gv2b = (const float*)d_in[17];
  const float* Wc  = (const float*)d_in[18];
  const float* bc  = (const float*)d_in[19];
  const float* lnw = (const float*)d_in[20];
  const float* lnb = (const float*)d_in[21];

  char* ws = (char*)d_ws;
  size_t off = 0;
  auto alloc = [&](size_t n) { char* p = ws + off; off += (n + 255) & ~(size_t)255; return p; };
  bf16_t* wW   = (bf16_t*)alloc(4ull * 3 * 1024 * 1024 * 2);
  bf16_t* wWc  = (bf16_t*)alloc(3ull * 128 * 128 * 2);
  bf16_t* xb   = (bf16_t*)alloc((size_t)BM * D * 2);
  float*  attn_o = (float*)alloc((size_t)BM * D * 4);
  bf16_t* q2p  = (bf16_t*)alloc((size_t)Bv * H * MP * HD * 2);
  bf16_t* kp   = (bf16_t*)alloc((size_t)Bv * H * MP * HD * 2);
  bf16_t* v1p  = (bf16_t*)alloc((size_t)Bv * H * MP * HD * 2);
  bf16_t* v2T  = (bf16_t*)alloc((size_t)Bv * H * HD * NP * 2);

  float* xf = (float*)d_out + (size_t)Bv * D;   // final/intermediate x lives in d_out

  cvt_kernel<<<1024, 256, 0, stream>>>(Wq2, wW + 0ull * 3 * 1024 * 1024, 3 * 1024 * 1024);
  cvt_kernel<<<1024, 256, 0, stream>>>(Wk,  wW + 1ull * 3 * 1024 * 1024, 3 * 1024 * 1024);
  cvt_kernel<<<1024, 256, 0, stream>>>(Wv1, wW + 2ull * 3 * 1024 * 1024, 3 * 1024 * 1024);
  cvt_kernel<<<1024, 256, 0, stream>>>(Wv2, wW + 3ull * 3 * 1024 * 1024, 3 * 1024 * 1024);
  cvt_kernel<<<64, 256, 0, stream>>>(Wc, wWc, 3 * 128 * 128);
  cvt_kernel<<<1024, 256, 0, stream>>>(att_feats, xb, BM * D);

  for (int i = 0; i < 3; ++i) {
    proj_kernel<<<1568, 256, 0, stream>>>(
        xb, wW,
        bq2, bk, bv1, bv2,
        gq2w, gkw, gv1w, gv2w,
        gq2b, gkb, gv1b, gv2b,
        i, q2p, kp, v1p, v2T);
    attn_kernel<<<dim3(256, 13), 64, 0, stream>>>(
        q2p, kp, v1p, v2T,
        wWc + (size_t)i * 128 * 128, bc + (size_t)i * 128,
        att_mask, attn_o);
    ln_kernel<<<BM, 256, 0, stream>>>(
        (i == 0) ? att_feats : xf, attn_o,
        lnw + (size_t)i * D, lnb + (size_t)i * D,
        xf, xb);
  }

  gv_kernel<<<dim3(Bv, 4), 256, 0, stream>>>(xf, att_mask, (float*)d_out);
}